// Round 1
// baseline (696.585 us; speedup 1.0000x reference)
//
#include <hip/hip_runtime.h>

// ---------------------------------------------------------------------------
// MultiHeadAttention: B=8, S=1024 (32x32), E=768, heads=12, depth=64
// inputs fp32; internal fp16 MFMA (f32 accum); outputs fp32 (out img + probs)
// ---------------------------------------------------------------------------

typedef _Float16 f16x8 __attribute__((ext_vector_type(8)));
typedef _Float16 f16x4 __attribute__((ext_vector_type(4)));
typedef float    f32x4 __attribute__((ext_vector_type(4)));

#define NB   8
#define NH   12
#define SEQ  1024
#define EMB  768
#define DEP  64

// LDS tile helpers: row-major [R][64] fp16 tiles, row stride 128B,
// XOR swizzle byte ^= (row&7)<<4  (read/write both sides).
__device__ __forceinline__ f16x8 frag_ld(const _Float16* t, int row, int kb) {
  const char* p = reinterpret_cast<const char*>(t) + ((row * 128 + kb) ^ ((row & 7) << 4));
  return *reinterpret_cast<const f16x8*>(p);
}
__device__ __forceinline__ void st16(_Float16* t, int row, int kb, uint4 v) {
  char* p = reinterpret_cast<char*>(t) + ((row * 128 + kb) ^ ((row & 7) << 4));
  *reinterpret_cast<uint4*>(p) = v;
}

// ---------------------------------------------------------------------------
// K0: x [b][c][s] fp32  ->  xt [b][s][c] fp16   (3 tensors via blockIdx.z)
// ---------------------------------------------------------------------------
__global__ __launch_bounds__(256) void transpose_kernel(
    const float* __restrict__ xq, const float* __restrict__ xk, const float* __restrict__ xv,
    _Float16* __restrict__ tq, _Float16* __restrict__ tk, _Float16* __restrict__ tv)
{
  const int st = blockIdx.x, ct = blockIdx.y;
  const int which = blockIdx.z >> 3, b = blockIdx.z & 7;
  const float* x = (which == 0) ? xq : (which == 1) ? xk : xv;
  _Float16*   t = (which == 0) ? tq : (which == 1) ? tk : tv;
  __shared__ float T[64][65];
  const int tid = threadIdx.x;
  const int s0 = st * 64, c0 = ct * 64;
#pragma unroll
  for (int p = 0; p < 4; ++p) {
    int ci = tid + p * 256;
    int rr = ci >> 4, g = ci & 15;               // rr = c row, g = s group of 4
    float4 v4 = *reinterpret_cast<const float4*>(
        x + ((size_t)b * EMB + c0 + rr) * SEQ + s0 + g * 4);
    T[rr][g * 4 + 0] = v4.x; T[rr][g * 4 + 1] = v4.y;
    T[rr][g * 4 + 2] = v4.z; T[rr][g * 4 + 3] = v4.w;
  }
  __syncthreads();
#pragma unroll
  for (int p = 0; p < 2; ++p) {
    int ci = tid + p * 256;
    int rr = ci >> 3, g = ci & 7;                // rr = s row, g = c group of 8
    f16x8 hv;
#pragma unroll
    for (int j = 0; j < 8; ++j) hv[j] = (_Float16)T[g * 8 + j][rr];
    *reinterpret_cast<f16x8*>(t + ((size_t)b * SEQ + s0 + rr) * EMB + c0 + g * 8) = hv;
  }
}

// ---------------------------------------------------------------------------
// K1: QKV projection.  Y[s,o] = sum_c xt[s,c]*W[o,c] + bias[o]  (q scaled 1/8)
// out fp16 [b][h][s][d].  64x64 tile, BK=64, 4 waves as 2x2 (each 32x32).
// ---------------------------------------------------------------------------
__global__ __launch_bounds__(256) void proj_kernel(
    const _Float16* __restrict__ tq, const _Float16* __restrict__ tk, const _Float16* __restrict__ tv,
    const float* __restrict__ wq, const float* __restrict__ bq,
    const float* __restrict__ wk, const float* __restrict__ bk,
    const float* __restrict__ wv, const float* __restrict__ bv,
    _Float16* __restrict__ Q, _Float16* __restrict__ K, _Float16* __restrict__ V)
{
  const int ot = blockIdx.x, st = blockIdx.y;
  const int which = blockIdx.z >> 3, b = blockIdx.z & 7;
  const _Float16* xt = (which == 0) ? tq : (which == 1) ? tk : tv;
  const float* W  = (which == 0) ? wq : (which == 1) ? wk : wv;
  const float* Bs = (which == 0) ? bq : (which == 1) ? bk : bv;
  _Float16* dst   = (which == 0) ? Q  : (which == 1) ? K  : V;
  const float scale = (which == 0) ? 0.125f : 1.0f;

  __shared__ _Float16 Al[64 * 64];   // A = xt rows (s), k = c
  __shared__ _Float16 Bl[64 * 64];   // B = W  rows (o), k = c
  const int tid = threadIdx.x;
  const int lane = tid & 63, wid = tid >> 6;
  const int l16 = lane & 15, lg = lane >> 4;
  const int wm = wid >> 1, wn = wid & 1;
  const int s0 = st * 64, o0 = ot * 64;
  const _Float16* xbase = xt + ((size_t)b * SEQ + s0) * EMB;

  f32x4 acc[2][2];
  const f32x4 zf = {0.f, 0.f, 0.f, 0.f};
  acc[0][0] = zf; acc[0][1] = zf; acc[1][0] = zf; acc[1][1] = zf;

  for (int kk = 0; kk < EMB; kk += 64) {
    __syncthreads();
#pragma unroll
    for (int p = 0; p < 2; ++p) {                        // A tile: fp16 16B chunks
      int ci = tid + p * 256;
      int rr = ci >> 3, g = ci & 7;
      uint4 d = *reinterpret_cast<const uint4*>(xbase + (size_t)rr * EMB + kk + g * 8);
      st16(Al, rr, g * 16, d);
    }
#pragma unroll
    for (int p = 0; p < 4; ++p) {                        // B tile: fp32->fp16
      int ci = tid + p * 256;
      int rr = ci >> 4, g4 = ci & 15;
      float4 w4 = *reinterpret_cast<const float4*>(W + (size_t)(o0 + rr) * EMB + kk + g4 * 4);
      f16x4 hv;
      hv[0] = (_Float16)w4.x; hv[1] = (_Float16)w4.y;
      hv[2] = (_Float16)w4.z; hv[3] = (_Float16)w4.w;
      char* p8 = reinterpret_cast<char*>(Bl) + ((rr * 128 + g4 * 8) ^ ((rr & 7) << 4));
      *reinterpret_cast<f16x4*>(p8) = hv;
    }
    __syncthreads();
#pragma unroll
    for (int h2 = 0; h2 < 2; ++h2) {
      const int kb = h2 * 64 + 16 * lg;
      f16x8 a0 = frag_ld(Al, wm * 32 + l16, kb);
      f16x8 a1 = frag_ld(Al, wm * 32 + 16 + l16, kb);
      f16x8 b0 = frag_ld(Bl, wn * 32 + l16, kb);
      f16x8 b1 = frag_ld(Bl, wn * 32 + 16 + l16, kb);
      acc[0][0] = __builtin_amdgcn_mfma_f32_16x16x32_f16(a0, b0, acc[0][0], 0, 0, 0);
      acc[0][1] = __builtin_amdgcn_mfma_f32_16x16x32_f16(a0, b1, acc[0][1], 0, 0, 0);
      acc[1][0] = __builtin_amdgcn_mfma_f32_16x16x32_f16(a1, b0, acc[1][0], 0, 0, 0);
      acc[1][1] = __builtin_amdgcn_mfma_f32_16x16x32_f16(a1, b1, acc[1][1], 0, 0, 0);
    }
  }
#pragma unroll
  for (int am = 0; am < 2; ++am)
#pragma unroll
    for (int bn = 0; bn < 2; ++bn) {
      int o = o0 + wn * 32 + bn * 16 + l16;
      float bias = Bs[o];
      int hh = o >> 6, dd = o & 63;
#pragma unroll
      for (int r = 0; r < 4; ++r) {
        int s = s0 + wm * 32 + am * 16 + 4 * lg + r;
        float y = (acc[am][bn][r] + bias) * scale;
        dst[(((size_t)b * NH + hh) * SEQ + s) * DEP + dd] = (_Float16)y;
      }
    }
}

// ---------------------------------------------------------------------------
// K2: attention.  Per block: one (b,h), 64 q rows. Two passes over 16 k-tiles.
// pass1: rowsum of exp(S); pass2: recompute S, write probs fp32, PV via LDS.
// 4 waves, each owns 16 q rows.
// ---------------------------------------------------------------------------
__global__ __launch_bounds__(256) void attn_kernel(
    const _Float16* __restrict__ Q, const _Float16* __restrict__ K,
    const _Float16* __restrict__ V,
    float* __restrict__ probs, _Float16* __restrict__ ctx)
{
  const int qt = blockIdx.x, h = blockIdx.y, b = blockIdx.z;
  const size_t bh = (size_t)b * NH + h;
  const _Float16* qp = Q + bh * SEQ * DEP;
  const _Float16* kp = K + bh * SEQ * DEP;
  const _Float16* vp = V + bh * SEQ * DEP;

  __shared__ _Float16 Ql[64 * 64], Kl[64 * 64], Vt[64 * 64], Pl[64 * 64];
  const int tid = threadIdx.x;
  const int lane = tid & 63, wid = tid >> 6;
  const int l16 = lane & 15, lg = lane >> 4;
  const f32x4 zf = {0.f, 0.f, 0.f, 0.f};

  // stage Q (rows qt*64..+63)
#pragma unroll
  for (int p = 0; p < 2; ++p) {
    int ci = tid + p * 256;
    int rr = ci >> 3, g = ci & 7;
    uint4 d = *reinterpret_cast<const uint4*>(qp + (size_t)(qt * 64 + rr) * DEP + g * 8);
    st16(Ql, rr, g * 16, d);
  }

  float rsum[4] = {0.f, 0.f, 0.f, 0.f};
  // ---- pass 1: row sums of exp ----
  for (int kt = 0; kt < 16; ++kt) {
    __syncthreads();
#pragma unroll
    for (int p = 0; p < 2; ++p) {
      int ci = tid + p * 256;
      int rr = ci >> 3, g = ci & 7;
      uint4 d = *reinterpret_cast<const uint4*>(kp + (size_t)(kt * 64 + rr) * DEP + g * 8);
      st16(Kl, rr, g * 16, d);
    }
    __syncthreads();
    f32x4 sa[4]; sa[0] = zf; sa[1] = zf; sa[2] = zf; sa[3] = zf;
#pragma unroll
    for (int h2 = 0; h2 < 2; ++h2) {
      const int kb = h2 * 64 + 16 * lg;
      f16x8 af = frag_ld(Ql, wid * 16 + l16, kb);
#pragma unroll
      for (int nt = 0; nt < 4; ++nt) {
        f16x8 bf = frag_ld(Kl, nt * 16 + l16, kb);
        sa[nt] = __builtin_amdgcn_mfma_f32_16x16x32_f16(af, bf, sa[nt], 0, 0, 0);
      }
    }
#pragma unroll
    for (int nt = 0; nt < 4; ++nt)
#pragma unroll
      for (int r = 0; r < 4; ++r) rsum[r] += __expf(sa[nt][r]);
  }
  // reduce across the 16 lanes holding different columns of the same rows
#pragma unroll
  for (int m = 1; m < 16; m <<= 1)
#pragma unroll
    for (int r = 0; r < 4; ++r) rsum[r] += __shfl_xor(rsum[r], m, 64);
  float inv[4];
#pragma unroll
  for (int r = 0; r < 4; ++r) inv[r] = 1.0f / rsum[r];

  f32x4 cacc[4]; cacc[0] = zf; cacc[1] = zf; cacc[2] = zf; cacc[3] = zf;
  // ---- pass 2: probs + PV ----
  for (int kt = 0; kt < 16; ++kt) {
    __syncthreads();
#pragma unroll
    for (int p = 0; p < 2; ++p) {
      int ci = tid + p * 256;
      int rr = ci >> 3, g = ci & 7;
      uint4 d = *reinterpret_cast<const uint4*>(kp + (size_t)(kt * 64 + rr) * DEP + g * 8);
      st16(Kl, rr, g * 16, d);
    }
    // V tile transposed into Vt[d][t]; per instruction all 64 lanes share a
    // d-row with consecutive t -> conflict-free scalar writes
#pragma unroll
    for (int p = 0; p < 2; ++p) {
      int g = wid + p * 4, tr = lane;
      f16x8 dv = *reinterpret_cast<const f16x8*>(vp + (size_t)(kt * 64 + tr) * DEP + g * 8);
#pragma unroll
      for (int j = 0; j < 8; ++j) {
        int drow = g * 8 + j;
        char* pB = reinterpret_cast<char*>(Vt) + ((drow * 128 + tr * 2) ^ ((drow & 7) << 4));
        *reinterpret_cast<_Float16*>(pB) = dv[j];
      }
    }
    __syncthreads();
    f32x4 sa[4]; sa[0] = zf; sa[1] = zf; sa[2] = zf; sa[3] = zf;
#pragma unroll
    for (int h2 = 0; h2 < 2; ++h2) {
      const int kb = h2 * 64 + 16 * lg;
      f16x8 af = frag_ld(Ql, wid * 16 + l16, kb);
#pragma unroll
      for (int nt = 0; nt < 4; ++nt) {
        f16x8 bf = frag_ld(Kl, nt * 16 + l16, kb);
        sa[nt] = __builtin_amdgcn_mfma_f32_16x16x32_f16(af, bf, sa[nt], 0, 0, 0);
      }
    }
#pragma unroll
    for (int nt = 0; nt < 4; ++nt)
#pragma unroll
      for (int r = 0; r < 4; ++r) {
        float pv = __expf(sa[nt][r]) * inv[r];
        int qrl = wid * 16 + 4 * lg + r;                 // local q row
        probs[(bh * SEQ + qt * 64 + qrl) * SEQ + kt * 64 + nt * 16 + l16] = pv;
        char* pP = reinterpret_cast<char*>(Pl) +
                   ((qrl * 128 + (nt * 16 + l16) * 2) ^ ((qrl & 7) << 4));
        *reinterpret_cast<_Float16*>(pP) = (_Float16)pv;
      }
    // PV: A = P (own wave rows), B = Vt
#pragma unroll
    for (int h2 = 0; h2 < 2; ++h2) {
      const int kb = h2 * 64 + 16 * lg;
      f16x8 af = frag_ld(Pl, wid * 16 + l16, kb);
#pragma unroll
      for (int dt = 0; dt < 4; ++dt) {
        f16x8 bf = frag_ld(Vt, dt * 16 + l16, kb);
        cacc[dt] = __builtin_amdgcn_mfma_f32_16x16x32_f16(af, bf, cacc[dt], 0, 0, 0);
      }
    }
  }
  // write ctx [b][s][e], e = h*64 + d
#pragma unroll
  for (int dt = 0; dt < 4; ++dt)
#pragma unroll
    for (int r = 0; r < 4; ++r) {
      int s = qt * 64 + wid * 16 + 4 * lg + r;
      int e = h * DEP + dt * 16 + l16;
      ctx[((size_t)b * SEQ + s) * EMB + e] = (_Float16)cacc[dt][r];
    }
}

// ---------------------------------------------------------------------------
// K3: fc.  out[b][o][s] = sum_c ctx[b][s][c]*fc_w[o][c] + fc_b[o]   (fp32 out)
// M = o, N = s  (coalesced fp32 stores over s)
// ---------------------------------------------------------------------------
__global__ __launch_bounds__(256) void fc_kernel(
    const _Float16* __restrict__ ctx, const float* __restrict__ W,
    const float* __restrict__ bias, float* __restrict__ out)
{
  const int st = blockIdx.x, ot = blockIdx.y, b = blockIdx.z;
  __shared__ _Float16 Al[64 * 64];   // W rows (o), k = c
  __shared__ _Float16 Bl[64 * 64];   // ctx rows (s), k = c
  const int tid = threadIdx.x;
  const int lane = tid & 63, wid = tid >> 6;
  const int l16 = lane & 15, lg = lane >> 4;
  const int wm = wid >> 1, wn = wid & 1;
  const int o0 = ot * 64, s0 = st * 64;

  f32x4 acc[2][2];
  const f32x4 zf = {0.f, 0.f, 0.f, 0.f};
  acc[0][0] = zf; acc[0][1] = zf; acc[1][0] = zf; acc[1][1] = zf;

  for (int kk = 0; kk < EMB; kk += 64) {
    __syncthreads();
#pragma unroll
    for (int p = 0; p < 4; ++p) {                        // A tile: fp32->fp16
      int ci = tid + p * 256;
      int rr = ci >> 4, g4 = ci & 15;
      float4 w4 = *reinterpret_cast<const float4*>(W + (size_t)(o0 + rr) * EMB + kk + g4 * 4);
      f16x4 hv;
      hv[0] = (_Float16)w4.x; hv[1] = (_Float16)w4.y;
      hv[2] = (_Float16)w4.z; hv[3] = (_Float16)w4.w;
      char* p8 = reinterpret_cast<char*>(Al) + ((rr * 128 + g4 * 8) ^ ((rr & 7) << 4));
      *reinterpret_cast<f16x4*>(p8) = hv;
    }
#pragma unroll
    for (int p = 0; p < 2; ++p) {                        // B tile: ctx fp16
      int ci = tid + p * 256;
      int rr = ci >> 3, g = ci & 7;
      uint4 d = *reinterpret_cast<const uint4*>(
          ctx + ((size_t)b * SEQ + s0 + rr) * EMB + kk + g * 8);
      st16(Bl, rr, g * 16, d);
    }
    __syncthreads();
#pragma unroll
    for (int h2 = 0; h2 < 2; ++h2) {
      const int kb = h2 * 64 + 16 * lg;
      f16x8 a0 = frag_ld(Al, wm * 32 + l16, kb);
      f16x8 a1 = frag_ld(Al, wm * 32 + 16 + l16, kb);
      f16x8 b0 = frag_ld(Bl, wn * 32 + l16, kb);
      f16x8 b1 = frag_ld(Bl, wn * 32 + 16 + l16, kb);
      acc[0][0] = __builtin_amdgcn_mfma_f32_16x16x32_f16(a0, b0, acc[0][0], 0, 0, 0);
      acc[0][1] = __builtin_amdgcn_mfma_f32_16x16x32_f16(a0, b1, acc[0][1], 0, 0, 0);
      acc[1][0] = __builtin_amdgcn_mfma_f32_16x16x32_f16(a1, b0, acc[1][0], 0, 0, 0);
      acc[1][1] = __builtin_amdgcn_mfma_f32_16x16x32_f16(a1, b1, acc[1][1], 0, 0, 0);
    }
  }
#pragma unroll
  for (int am = 0; am < 2; ++am)
#pragma unroll
    for (int r = 0; r < 4; ++r) {
      int o = o0 + wm * 32 + am * 16 + 4 * lg + r;
      float bo = bias[o];
#pragma unroll
      for (int bn = 0; bn < 2; ++bn) {
        int s = s0 + wn * 32 + bn * 16 + l16;
        out[((size_t)b * EMB + o) * SEQ + s] = acc[am][bn][r] + bo;
      }
    }
}

// ---------------------------------------------------------------------------
extern "C" void kernel_launch(void* const* d_in, const int* in_sizes, int n_in,
                              void* d_out, int out_size, void* d_ws, size_t ws_size,
                              hipStream_t stream)
{
  const float* xq = (const float*)d_in[0];
  const float* xk = (const float*)d_in[1];
  const float* xv = (const float*)d_in[2];
  const float* wq = (const float*)d_in[3];
  const float* bq = (const float*)d_in[4];
  const float* wk = (const float*)d_in[5];
  const float* bk = (const float*)d_in[6];
  const float* wv = (const float*)d_in[7];
  const float* bv = (const float*)d_in[8];
  const float* fw = (const float*)d_in[9];
  const float* fb = (const float*)d_in[10];

  float* out   = (float*)d_out;
  float* probs = out + (size_t)NB * EMB * SEQ;          // out image first, then probs

  const size_t XT = (size_t)NB * SEQ * EMB;             // elements per fp16 tensor
  if (ws_size < XT * 2 * 7) return;                     // need ~88 MB scratch
  _Float16* ws = (_Float16*)d_ws;
  _Float16* tq = ws;
  _Float16* tk = ws + XT;
  _Float16* tv = ws + 2 * XT;
  _Float16* Q  = ws + 3 * XT;
  _Float16* K  = ws + 4 * XT;
  _Float16* V  = ws + 5 * XT;
  _Float16* CT = ws + 6 * XT;

  transpose_kernel<<<dim3(16, 12, 24), 256, 0, stream>>>(xq, xk, xv, tq, tk, tv);
  proj_kernel<<<dim3(12, 16, 24), 256, 0, stream>>>(tq, tk, tv, wq, bq, wk, bk, wv, bv, Q, K, V);
  attn_kernel<<<dim3(16, 12, 8), 256, 0, stream>>>(Q, K, V, probs, CT);
  fc_kernel<<<dim3(16, 12, 8), 256, 0, stream>>>(CT, fw, fb, out);
}